// Round 1
// baseline (525.097 us; speedup 1.0000x reference)
//
#include <hip/hip_runtime.h>
#include <hip/hip_bf16.h>

typedef __attribute__((ext_vector_type(8))) short bf16x8;
typedef __attribute__((ext_vector_type(4))) float f32x4;
typedef __attribute__((ext_vector_type(4))) int   i32x4;

#define D_MODEL 2048
#define NTOK    4096   // B*S
#define NH      16
#define HD      128
#define SEQ     2048

__device__ __forceinline__ short f2bf(float f) {
  unsigned u = __builtin_bit_cast(unsigned, f);
  unsigned r = u + 0x7FFFu + ((u >> 16) & 1u);   // RNE
  return (short)(r >> 16);
}
__device__ __forceinline__ float bf2f(short s) {
  return __builtin_bit_cast(float, ((unsigned)(unsigned short)s) << 16);
}

// async global->LDS, 16B per lane. LDS dst must be wave-uniform; HW writes lane i at dst + i*16.
__device__ __forceinline__ void gload_lds16(const void* g, void* l) {
  typedef __attribute__((address_space(1))) const unsigned gu32;
  typedef __attribute__((address_space(3))) unsigned lu32;
  __builtin_amdgcn_global_load_lds((gu32*)(uintptr_t)g,
                                   (lu32*)(unsigned)(uintptr_t)l, 16, 0, 0);
}

// ---------------- 1. fp32 -> bf16 cast (vectorized) ----------------
__global__ __launch_bounds__(256) void cast_bf16(const float* __restrict__ in,
                                                 short* __restrict__ out, int n4) {
  int i = blockIdx.x * 256 + threadIdx.x;
  if (i >= n4) return;
  float4 v = ((const float4*)in)[i];
  short4 o;
  o.x = f2bf(v.x); o.y = f2bf(v.y); o.z = f2bf(v.z); o.w = f2bf(v.w);
  ((short4*)out)[i] = o;
}

// ---------------- 2. W (KxN) -> W^T (NxK) bf16, LDS-tiled ----------------
__global__ __launch_bounds__(256) void wtrans(const float* __restrict__ w0,
                                              const float* __restrict__ w1,
                                              const float* __restrict__ w2,
                                              const float* __restrict__ w3,
                                              short* __restrict__ wt) {
  int z = blockIdx.z;
  const float* W = (z == 0) ? w0 : (z == 1) ? w1 : (z == 2) ? w2 : w3;
  short* O = wt + (size_t)z * D_MODEL * D_MODEL;
  int n0 = blockIdx.x * 64, k0 = blockIdx.y * 64;
  __shared__ short T[64 * 136];
  int tid = threadIdx.x;
#pragma unroll
  for (int it = 0; it < 4; ++it) {
    int f = it * 256 + tid, kk = f >> 4, nc = f & 15;
    float4 v = *(const float4*)&W[(size_t)(k0 + kk) * D_MODEL + n0 + nc * 4];
    short4 o;
    o.x = f2bf(v.x); o.y = f2bf(v.y); o.z = f2bf(v.z); o.w = f2bf(v.w);
    *(short4*)&T[kk * 136 + nc * 4] = o;
  }
  __syncthreads();
#pragma unroll
  for (int it = 0; it < 4; ++it) {
    int u = it * 256 + tid, nn = u >> 4, kc = u & 15;
    short4 o;
    o.x = T[(kc * 4 + 0) * 136 + nn];
    o.y = T[(kc * 4 + 1) * 136 + nn];
    o.z = T[(kc * 4 + 2) * 136 + nn];
    o.w = T[(kc * 4 + 3) * 136 + nn];
    *(short4*)&O[(size_t)(n0 + nn) * D_MODEL + k0 + kc * 4] = o;
  }
}

// ---------------- 3/7. GEMM  C[M,N] = A[M,K] * Bt[N,K]^T  (m97 structure) ----------------
template <bool OUTBF16>
__global__ __launch_bounds__(256) void gemm_bt(const short* __restrict__ A,
                                               const short* __restrict__ Bt,
                                               void* __restrict__ Cv,
                                               int M, int N, int K) {
  __shared__ short As[128 * 32];
  __shared__ short Bs[128 * 32];
  int tid = threadIdx.x;
  int w = tid >> 6, lane = tid & 63, c = lane & 15, g = lane >> 4;
  int z = blockIdx.z;
  const short* Bb = Bt + (size_t)z * K * N;
  int m0 = blockIdx.y * 128, n0 = blockIdx.x * 128;
  int wm = w >> 1, wn = w & 1;
  f32x4 acc[4][4] = {};
  int lrow = lane >> 2, lk = (lane & 3) * 8;

  for (int kk = 0; kk < K; kk += 32) {
    __syncthreads();
#pragma unroll
    for (int q = 0; q < 2; ++q) {
      int ch = 2 * w + q;  // wave-uniform chunk id (16 rows of 32 bf16 = 1KB)
      gload_lds16(A  + (size_t)(m0 + ch * 16 + lrow) * K + kk + lk, &As[ch * 512]);
      gload_lds16(Bb + (size_t)(n0 + ch * 16 + lrow) * K + kk + lk, &Bs[ch * 512]);
    }
    __syncthreads();
    bf16x8 af[4], bfr[4];
#pragma unroll
    for (int mi = 0; mi < 4; ++mi)
      af[mi] = *(const bf16x8*)&As[(wm * 64 + mi * 16 + c) * 32 + g * 8];
#pragma unroll
    for (int ni = 0; ni < 4; ++ni)
      bfr[ni] = *(const bf16x8*)&Bs[(wn * 64 + ni * 16 + c) * 32 + g * 8];
#pragma unroll
    for (int mi = 0; mi < 4; ++mi)
#pragma unroll
      for (int ni = 0; ni < 4; ++ni)
        acc[mi][ni] = __builtin_amdgcn_mfma_f32_16x16x32_bf16(af[mi], bfr[ni],
                                                              acc[mi][ni], 0, 0, 0);
  }
  int row0 = m0 + wm * 64, col0 = n0 + wn * 64;
  if (OUTBF16) {
    short* Cb = (short*)Cv + (size_t)z * M * N;
#pragma unroll
    for (int mi = 0; mi < 4; ++mi)
#pragma unroll
      for (int ni = 0; ni < 4; ++ni)
#pragma unroll
        for (int i = 0; i < 4; ++i)
          Cb[(size_t)(row0 + mi * 16 + g * 4 + i) * N + col0 + ni * 16 + c] =
              f2bf(acc[mi][ni][i]);
  } else {
    float* Cf = (float*)Cv;
#pragma unroll
    for (int mi = 0; mi < 4; ++mi)
#pragma unroll
      for (int ni = 0; ni < 4; ++ni)
#pragma unroll
        for (int i = 0; i < 4; ++i)
          Cf[(size_t)(row0 + mi * 16 + g * 4 + i) * N + col0 + ni * 16 + c] =
              acc[mi][ni][i];
  }
}

// ---------------- 4. fused RMSNorm + RoPE (q,k), one wave per (token,head) ----------------
__global__ __launch_bounds__(256) void norm_rope(const short* __restrict__ qkv16,
                                                 const float* __restrict__ cosb,
                                                 const float* __restrict__ sinb,
                                                 const float* __restrict__ gq,
                                                 const float* __restrict__ gk,
                                                 short* __restrict__ qn,
                                                 short* __restrict__ kn) {
  int z = blockIdx.y;  // 0=q, 1=k
  const short* X = qkv16 + (size_t)z * NTOK * D_MODEL;
  const float* gg = z ? gk : gq;
  short* O = z ? kn : qn;
  int w = threadIdx.x >> 6, lane = threadIdx.x & 63;
  int p = blockIdx.x * 4 + w;          // (token,head) pair
  int token = p >> 4, h = p & 15;
  int v = *(const int*)&X[(size_t)token * D_MODEL + h * HD + lane * 2];
  float x0 = bf2f((short)(v & 0xffff));
  float x1 = bf2f((short)((unsigned)v >> 16));
  float ss = x0 * x0 + x1 * x1;
#pragma unroll
  for (int mk = 32; mk; mk >>= 1) ss += __shfl_xor(ss, mk);
  float rs = rsqrtf(ss * (1.f / 128.f) + 1e-5f);
  float xr = x0 * rs * gg[lane * 2];
  float xi = x1 * rs * gg[lane * 2 + 1];
  float cc = cosb[(size_t)token * 64 + lane];
  float sn = sinb[(size_t)token * 64 + lane];
  float or_ = xr * cc - xi * sn;
  float oi_ = xr * sn + xi * cc;
  int b = token >> 11, sidx = token & 2047;
  size_t dst = ((size_t)(b * NH + h) * SEQ + sidx) * HD + lane * 2;
  unsigned pk = (unsigned)(unsigned short)f2bf(or_) |
                ((unsigned)(unsigned short)f2bf(oi_) << 16);
  *(unsigned*)&O[dst] = pk;
}

// ---------------- 5. V (token-major bf16) -> V^T (B,H,128,S) ----------------
__global__ __launch_bounds__(256) void vtrans(const short* __restrict__ v16,
                                              short* __restrict__ vt) {
  int st = blockIdx.x, bh = blockIdx.y;
  int b = bh >> 4, h = bh & 15;
  int t0 = b * SEQ + st * 64;
  __shared__ short Lt[64 * 136];
  int tid = threadIdx.x;
#pragma unroll
  for (int it = 0; it < 4; ++it) {
    int f = it * 256 + tid, tk = f >> 4, ch = f & 15;
    *(i32x4*)&Lt[tk * 136 + ch * 8] =
        *(const i32x4*)&v16[(size_t)(t0 + tk) * D_MODEL + h * HD + ch * 8];
  }
  __syncthreads();
#pragma unroll
  for (int it = 0; it < 4; ++it) {
    int u = it * 256 + tid, d = u >> 3, kg = u & 7;
    bf16x8 o;
#pragma unroll
    for (int j = 0; j < 8; ++j) o[j] = Lt[(kg * 8 + j) * 136 + d];
    *(bf16x8*)&vt[(size_t)(bh * HD + d) * SEQ + st * 64 + kg * 8] = o;
  }
}

// ---------------- 6. flash attention: 4 waves x 16 q-rows, KV tile 64 ----------------
__global__ __launch_bounds__(256) void flash(const short* __restrict__ qn,
                                             const short* __restrict__ kn,
                                             const short* __restrict__ vt,
                                             short* __restrict__ attn) {
  __shared__ short Ks[64 * 136];   // [key][d], pad->row stride 68 words (bank-optimal)
  __shared__ short Vs[128 * 72];   // [d][key]
  __shared__ short Ps[4 * 16 * 72];// per-wave P [q][key]
  int tid = threadIdx.x, w = tid >> 6, lane = tid & 63, c = lane & 15, g = lane >> 4;
  int bh = blockIdx.y;
  int q0 = blockIdx.x * 64 + w * 16;
  const size_t base = (size_t)bh * SEQ * HD;
  bf16x8 qf[4];
#pragma unroll
  for (int kf = 0; kf < 4; ++kf)
    qf[kf] = *(const bf16x8*)&qn[base + (size_t)(q0 + c) * HD + kf * 32 + g * 8];
  f32x4 acc[8] = {};
  float m_[4], l_[4];
#pragma unroll
  for (int i = 0; i < 4; ++i) { m_[i] = -1e30f; l_[i] = 0.f; }
  const float scale = 0.08838834764831845f;  // 1/sqrt(128)

  for (int t = 0; t < SEQ / 64; ++t) {
    int k0 = t * 64;
    __syncthreads();
#pragma unroll
    for (int it = 0; it < 4; ++it) {
      int f = it * 256 + tid;
      int key = f >> 4, ch = f & 15;
      *(i32x4*)&Ks[key * 136 + ch * 8] =
          *(const i32x4*)&kn[base + (size_t)(k0 + key) * HD + ch * 8];
      int d = f >> 3, kc = f & 7;
      *(i32x4*)&Vs[d * 72 + kc * 8] =
          *(const i32x4*)&vt[(size_t)(bh * HD + d) * SEQ + k0 + kc * 8];
    }
    __syncthreads();

    float s[4][4];
#pragma unroll
    for (int kt = 0; kt < 4; ++kt) {
      f32x4 sa = {0.f, 0.f, 0.f, 0.f};
#pragma unroll
      for (int kf = 0; kf < 4; ++kf) {
        bf16x8 kb = *(const bf16x8*)&Ks[(kt * 16 + c) * 136 + kf * 32 + g * 8];
        sa = __builtin_amdgcn_mfma_f32_16x16x32_bf16(qf[kf], kb, sa, 0, 0, 0);
      }
#pragma unroll
      for (int i = 0; i < 4; ++i) s[kt][i] = sa[i] * scale;
    }

    float alpha[4], rs[4];
#pragma unroll
    for (int i = 0; i < 4; ++i) {
      float mx = fmaxf(fmaxf(s[0][i], s[1][i]), fmaxf(s[2][i], s[3][i]));
      mx = fmaxf(mx, __shfl_xor(mx, 1));
      mx = fmaxf(mx, __shfl_xor(mx, 2));
      mx = fmaxf(mx, __shfl_xor(mx, 4));
      mx = fmaxf(mx, __shfl_xor(mx, 8));
      float mn = fmaxf(m_[i], mx);
      alpha[i] = __expf(m_[i] - mn);
      m_[i] = mn;
      rs[i] = 0.f;
    }
#pragma unroll
    for (int kt = 0; kt < 4; ++kt)
#pragma unroll
      for (int i = 0; i < 4; ++i) {
        float p = __expf(s[kt][i] - m_[i]);
        rs[i] += p;
        Ps[w * 1152 + (g * 4 + i) * 72 + kt * 16 + c] = f2bf(p);
      }
#pragma unroll
    for (int i = 0; i < 4; ++i) {
      float r = rs[i];
      r += __shfl_xor(r, 1); r += __shfl_xor(r, 2);
      r += __shfl_xor(r, 4); r += __shfl_xor(r, 8);
      l_[i] = l_[i] * alpha[i] + r;
    }
#pragma unroll
    for (int db = 0; db < 8; ++db)
#pragma unroll
      for (int i = 0; i < 4; ++i) acc[db][i] *= alpha[i];

#pragma unroll
    for (int kf2 = 0; kf2 < 2; ++kf2) {
      bf16x8 pa = *(const bf16x8*)&Ps[w * 1152 + c * 72 + kf2 * 32 + g * 8];
#pragma unroll
      for (int db = 0; db < 8; ++db) {
        bf16x8 vb = *(const bf16x8*)&Vs[(db * 16 + c) * 72 + kf2 * 32 + g * 8];
        acc[db] = __builtin_amdgcn_mfma_f32_16x16x32_bf16(pa, vb, acc[db], 0, 0, 0);
      }
    }
  }

  int b = bh >> 4, h = bh & 15;
#pragma unroll
  for (int i = 0; i < 4; ++i) l_[i] = 1.f / l_[i];
#pragma unroll
  for (int db = 0; db < 8; ++db)
#pragma unroll
    for (int i = 0; i < 4; ++i) {
      int r = q0 + g * 4 + i;
      attn[(size_t)(b * SEQ + r) * D_MODEL + h * HD + db * 16 + c] =
          f2bf(acc[db][i] * l_[i]);
    }
}

// ---------------- launch ----------------
extern "C" void kernel_launch(void* const* d_in, const int* in_sizes, int n_in,
                              void* d_out, int out_size, void* d_ws, size_t ws_size,
                              hipStream_t stream) {
  const float* hs   = (const float*)d_in[0];
  const float* fcos = (const float*)d_in[1];
  const float* fsin = (const float*)d_in[2];
  const float* Wq   = (const float*)d_in[3];
  const float* Wk   = (const float*)d_in[4];
  const float* Wv   = (const float*)d_in[5];
  const float* Wo   = (const float*)d_in[6];
  const float* gq   = (const float*)d_in[7];
  const float* gk   = (const float*)d_in[8];

  char* ws = (char*)d_ws;
  short* hs16  = (short*)ws;                        // 16,777,216 B
  short* Wt    = (short*)(ws + 16777216);           // 33,554,432 B (4 matrices, N-major)
  short* qkv16 = (short*)(ws + 50331648);           // 50,331,648 B (q,k,v bf16 token-major)
  short* qn    = (short*)(ws + 100663296);          // 16,777,216 B (B,H,S,128)
  short* kn    = (short*)(ws + 117440512);          // 16,777,216 B
  short* vt    = (short*)(ws + 134217728);          // 16,777,216 B (B,H,128,S)
  short* attn16 = qkv16;  // reuse q slot (dead after norm_rope)

  cast_bf16<<<8192, 256, 0, stream>>>(hs, hs16, NTOK * D_MODEL / 4);
  wtrans<<<dim3(32, 32, 4), 256, 0, stream>>>(Wq, Wk, Wv, Wo, Wt);
  gemm_bt<true><<<dim3(16, 32, 3), 256, 0, stream>>>(hs16, Wt, qkv16,
                                                     NTOK, D_MODEL, D_MODEL);
  norm_rope<<<dim3(16384, 2), 256, 0, stream>>>(qkv16, fcos, fsin, gq, gk, qn, kn);
  vtrans<<<dim3(32, 32), 256, 0, stream>>>(qkv16 + (size_t)2 * NTOK * D_MODEL, vt);
  flash<<<dim3(32, 32), 256, 0, stream>>>(qn, kn, vt, attn16);
  gemm_bt<false><<<dim3(16, 32, 1), 256, 0, stream>>>(attn16,
                                                      Wt + (size_t)3 * D_MODEL * D_MODEL,
                                                      d_out, NTOK, D_MODEL, D_MODEL);
}

// Round 2
// 410.908 us; speedup vs baseline: 1.2779x; 1.2779x over previous
//
#include <hip/hip_runtime.h>
#include <hip/hip_bf16.h>

typedef __attribute__((ext_vector_type(8))) short bf16x8;
typedef __attribute__((ext_vector_type(4))) float f32x4;
typedef __attribute__((ext_vector_type(4))) int   i32x4;

#define D_MODEL 2048
#define NTOK    4096   // B*S
#define NH      16
#define HD      128
#define SEQ     2048

__device__ __forceinline__ short f2bf(float f) {
  unsigned u = __builtin_bit_cast(unsigned, f);
  unsigned r = u + 0x7FFFu + ((u >> 16) & 1u);   // RNE
  return (short)(r >> 16);
}
__device__ __forceinline__ float bf2f(short s) {
  return __builtin_bit_cast(float, ((unsigned)(unsigned short)s) << 16);
}

// async global->LDS, 16B per lane. LDS dst must be wave-uniform; HW writes lane i at dst + i*16.
__device__ __forceinline__ void gload_lds16(const void* g, void* l) {
  typedef __attribute__((address_space(1))) const unsigned gu32;
  typedef __attribute__((address_space(3))) unsigned lu32;
  __builtin_amdgcn_global_load_lds((gu32*)(uintptr_t)g,
                                   (lu32*)(unsigned)(uintptr_t)l, 16, 0, 0);
}

// ---------------- 1. fp32 -> bf16 cast (vectorized) ----------------
__global__ __launch_bounds__(256) void cast_bf16(const float* __restrict__ in,
                                                 short* __restrict__ out, int n4) {
  int i = blockIdx.x * 256 + threadIdx.x;
  if (i >= n4) return;
  float4 v = ((const float4*)in)[i];
  short4 o;
  o.x = f2bf(v.x); o.y = f2bf(v.y); o.z = f2bf(v.z); o.w = f2bf(v.w);
  ((short4*)out)[i] = o;
}

// ---------------- 2. W (KxN) -> W^T (NxK) bf16, LDS-tiled ----------------
__global__ __launch_bounds__(256) void wtrans(const float* __restrict__ w0,
                                              const float* __restrict__ w1,
                                              const float* __restrict__ w2,
                                              const float* __restrict__ w3,
                                              short* __restrict__ wt) {
  int z = blockIdx.z;
  const float* W = (z == 0) ? w0 : (z == 1) ? w1 : (z == 2) ? w2 : w3;
  short* O = wt + (size_t)z * D_MODEL * D_MODEL;
  int n0 = blockIdx.x * 64, k0 = blockIdx.y * 64;
  __shared__ short T[64 * 136];
  int tid = threadIdx.x;
#pragma unroll
  for (int it = 0; it < 4; ++it) {
    int f = it * 256 + tid, kk = f >> 4, nc = f & 15;
    float4 v = *(const float4*)&W[(size_t)(k0 + kk) * D_MODEL + n0 + nc * 4];
    short4 o;
    o.x = f2bf(v.x); o.y = f2bf(v.y); o.z = f2bf(v.z); o.w = f2bf(v.w);
    *(short4*)&T[kk * 136 + nc * 4] = o;
  }
  __syncthreads();
#pragma unroll
  for (int it = 0; it < 4; ++it) {
    int u = it * 256 + tid, nn = u >> 4, kc = u & 15;
    short4 o;
    o.x = T[(kc * 4 + 0) * 136 + nn];
    o.y = T[(kc * 4 + 1) * 136 + nn];
    o.z = T[(kc * 4 + 2) * 136 + nn];
    o.w = T[(kc * 4 + 3) * 136 + nn];
    *(short4*)&O[(size_t)(n0 + nn) * D_MODEL + k0 + kc * 4] = o;
  }
}

// ---------------- 3/7. GEMM  C[M,N] = A[M,K] * Bt[N,K]^T  (m97 structure) ----------------
template <bool OUTBF16>
__global__ __launch_bounds__(256) void gemm_bt(const short* __restrict__ A,
                                               const short* __restrict__ Bt,
                                               void* __restrict__ Cv,
                                               int M, int N, int K) {
  __shared__ short As[128 * 32];
  __shared__ short Bs[128 * 32];
  int tid = threadIdx.x;
  int w = tid >> 6, lane = tid & 63, c = lane & 15, g = lane >> 4;
  int z = blockIdx.z;
  const short* Bb = Bt + (size_t)z * K * N;
  int m0 = blockIdx.y * 128, n0 = blockIdx.x * 128;
  int wm = w >> 1, wn = w & 1;
  f32x4 acc[4][4] = {};
  int lrow = lane >> 2, lk = (lane & 3) * 8;

  for (int kk = 0; kk < K; kk += 32) {
    __syncthreads();
#pragma unroll
    for (int q = 0; q < 2; ++q) {
      int ch = 2 * w + q;  // wave-uniform chunk id (16 rows of 32 bf16 = 1KB)
      gload_lds16(A  + (size_t)(m0 + ch * 16 + lrow) * K + kk + lk, &As[ch * 512]);
      gload_lds16(Bb + (size_t)(n0 + ch * 16 + lrow) * K + kk + lk, &Bs[ch * 512]);
    }
    __syncthreads();
    bf16x8 af[4], bfr[4];
#pragma unroll
    for (int mi = 0; mi < 4; ++mi)
      af[mi] = *(const bf16x8*)&As[(wm * 64 + mi * 16 + c) * 32 + g * 8];
#pragma unroll
    for (int ni = 0; ni < 4; ++ni)
      bfr[ni] = *(const bf16x8*)&Bs[(wn * 64 + ni * 16 + c) * 32 + g * 8];
#pragma unroll
    for (int mi = 0; mi < 4; ++mi)
#pragma unroll
      for (int ni = 0; ni < 4; ++ni)
        acc[mi][ni] = __builtin_amdgcn_mfma_f32_16x16x32_bf16(af[mi], bfr[ni],
                                                              acc[mi][ni], 0, 0, 0);
  }
  int row0 = m0 + wm * 64, col0 = n0 + wn * 64;
  if (OUTBF16) {
    short* Cb = (short*)Cv + (size_t)z * M * N;
#pragma unroll
    for (int mi = 0; mi < 4; ++mi)
#pragma unroll
      for (int ni = 0; ni < 4; ++ni)
#pragma unroll
        for (int i = 0; i < 4; ++i)
          Cb[(size_t)(row0 + mi * 16 + g * 4 + i) * N + col0 + ni * 16 + c] =
              f2bf(acc[mi][ni][i]);
  } else {
    float* Cf = (float*)Cv;
#pragma unroll
    for (int mi = 0; mi < 4; ++mi)
#pragma unroll
      for (int ni = 0; ni < 4; ++ni)
#pragma unroll
        for (int i = 0; i < 4; ++i)
          Cf[(size_t)(row0 + mi * 16 + g * 4 + i) * N + col0 + ni * 16 + c] =
              acc[mi][ni][i];
  }
}

// ---------------- 4. fused RMSNorm + RoPE (q,k), one wave per (token,head) ----------------
__global__ __launch_bounds__(256) void norm_rope(const short* __restrict__ qkv16,
                                                 const float* __restrict__ cosb,
                                                 const float* __restrict__ sinb,
                                                 const float* __restrict__ gq,
                                                 const float* __restrict__ gk,
                                                 short* __restrict__ qn,
                                                 short* __restrict__ kn) {
  int z = blockIdx.y;  // 0=q, 1=k
  const short* X = qkv16 + (size_t)z * NTOK * D_MODEL;
  const float* gg = z ? gk : gq;
  short* O = z ? kn : qn;
  int w = threadIdx.x >> 6, lane = threadIdx.x & 63;
  int p = blockIdx.x * 4 + w;          // (token,head) pair
  int token = p >> 4, h = p & 15;
  int v = *(const int*)&X[(size_t)token * D_MODEL + h * HD + lane * 2];
  float x0 = bf2f((short)(v & 0xffff));
  float x1 = bf2f((short)((unsigned)v >> 16));
  float ss = x0 * x0 + x1 * x1;
#pragma unroll
  for (int mk = 32; mk; mk >>= 1) ss += __shfl_xor(ss, mk);
  float rs = rsqrtf(ss * (1.f / 128.f) + 1e-5f);
  float xr = x0 * rs * gg[lane * 2];
  float xi = x1 * rs * gg[lane * 2 + 1];
  float cc = cosb[(size_t)token * 64 + lane];
  float sn = sinb[(size_t)token * 64 + lane];
  float or_ = xr * cc - xi * sn;
  float oi_ = xr * sn + xi * cc;
  int b = token >> 11, sidx = token & 2047;
  size_t dst = ((size_t)(b * NH + h) * SEQ + sidx) * HD + lane * 2;
  unsigned pk = (unsigned)(unsigned short)f2bf(or_) |
                ((unsigned)(unsigned short)f2bf(oi_) << 16);
  *(unsigned*)&O[dst] = pk;
}

// ---------------- 5. V (token-major bf16) -> V^T (B,H,128,S) ----------------
__global__ __launch_bounds__(256) void vtrans(const short* __restrict__ v16,
                                              short* __restrict__ vt) {
  int st = blockIdx.x, bh = blockIdx.y;
  int b = bh >> 4, h = bh & 15;
  int t0 = b * SEQ + st * 64;
  __shared__ short Lt[64 * 136];
  int tid = threadIdx.x;
#pragma unroll
  for (int it = 0; it < 4; ++it) {
    int f = it * 256 + tid, tk = f >> 4, ch = f & 15;
    *(i32x4*)&Lt[tk * 136 + ch * 8] =
        *(const i32x4*)&v16[(size_t)(t0 + tk) * D_MODEL + h * HD + ch * 8];
  }
  __syncthreads();
#pragma unroll
  for (int it = 0; it < 4; ++it) {
    int u = it * 256 + tid, d = u >> 3, kg = u & 7;
    bf16x8 o;
#pragma unroll
    for (int j = 0; j < 8; ++j) o[j] = Lt[(kg * 8 + j) * 136 + d];
    *(bf16x8*)&vt[(size_t)(bh * HD + d) * SEQ + st * 64 + kg * 8] = o;
  }
}

// ---------------- 6. flash attention: dbuf K/V via global_load_lds + XOR swizzle ----------------
// K tile: [64 rows][256B] (row = key). V tile: [128 rows][128B] (row = d).
// Swizzle involution: physbyte = row*RB + (colbyte ^ ((row&7)<<4)); applied on
// BOTH the gload_lds global source (pre-swizzle) and the ds_read address.
__global__ __launch_bounds__(256) void flash(const short* __restrict__ qn,
                                             const short* __restrict__ kn,
                                             const short* __restrict__ vt,
                                             short* __restrict__ attn) {
  __shared__ short Ks[2][64 * 128];   // 2 x 16KB, linear+swizzled
  __shared__ short Vs[2][128 * 64];   // 2 x 16KB, linear+swizzled
  __shared__ short Ps[4 * 16 * 72];   // per-wave P [q][key], padded
  int tid = threadIdx.x, w = tid >> 6, lane = tid & 63, c = lane & 15, g = lane >> 4;
  int bh = blockIdx.y;
  int q0 = blockIdx.x * 64 + w * 16;
  const size_t base = (size_t)bh * SEQ * HD;
  const short* Kg = kn + base;                 // key rows contiguous (256B each)
  const short* Vg = vt + base;                 // d rows, stride SEQ shorts

  bf16x8 qf[4];
#pragma unroll
  for (int kf = 0; kf < 4; ++kf)
    qf[kf] = *(const bf16x8*)&qn[base + (size_t)(q0 + c) * HD + kf * 32 + g * 8];

  f32x4 acc[8] = {};
  float m_[4], l_[4];
#pragma unroll
  for (int i = 0; i < 4; ++i) { m_[i] = -1e30f; l_[i] = 0.f; }
  const float scale = 0.08838834764831845f;  // 1/sqrt(128)

  // per-lane pre-swizzled global source offsets (shorts) for the 4 chunks this wave stages
  int ksrc[4], vsrc[4];
#pragma unroll
  for (int p = 0; p < 4; ++p) {
    int ch = w * 4 + p;
    int o = ch * 1024 + lane * 16;                       // linear LDS byte offset
    int kr = o >> 8, kc = o & 255;                       // K: 256B rows
    ksrc[p] = kr * HD + ((kc ^ ((kr & 7) << 4)) >> 1);
    int vr = o >> 7, vc = o & 127;                       // V: 128B rows
    vsrc[p] = vr * SEQ + ((vc ^ ((vr & 7) << 4)) >> 1);
  }

  // prologue: stage tile 0 into buffer 0
#pragma unroll
  for (int p = 0; p < 4; ++p) {
    int ch = w * 4 + p;
    gload_lds16(Kg + ksrc[p], (char*)&Ks[0][0] + ch * 1024);
    gload_lds16(Vg + vsrc[p], (char*)&Vs[0][0] + ch * 1024);
  }

  int cur = 0;
  for (int t = 0; t < SEQ / 64; ++t) {
    // Single barrier per iter: its vmcnt(0) drain makes buf[cur] ready, and all
    // waves have finished reading buf[cur^1] (last iter) -> safe to restage it.
    __syncthreads();
    if (t + 1 < SEQ / 64) {
      int k0n = (t + 1) * 64;
#pragma unroll
      for (int p = 0; p < 4; ++p) {
        int ch = w * 4 + p;
        gload_lds16(Kg + (size_t)k0n * HD + ksrc[p], (char*)&Ks[cur ^ 1][0] + ch * 1024);
        gload_lds16(Vg + k0n + vsrc[p],              (char*)&Vs[cur ^ 1][0] + ch * 1024);
      }
    }
    const char* Kb = (const char*)&Ks[cur][0];
    const char* Vb = (const char*)&Vs[cur][0];

    float s[4][4];
    __builtin_amdgcn_s_setprio(1);
#pragma unroll
    for (int kt = 0; kt < 4; ++kt) {
      f32x4 sa = {0.f, 0.f, 0.f, 0.f};
#pragma unroll
      for (int kf = 0; kf < 4; ++kf) {
        int row = kt * 16 + c, colb = kf * 64 + g * 16;
        bf16x8 kb = *(const bf16x8*)(Kb + row * 256 + (colb ^ ((row & 7) << 4)));
        sa = __builtin_amdgcn_mfma_f32_16x16x32_bf16(qf[kf], kb, sa, 0, 0, 0);
      }
#pragma unroll
      for (int i = 0; i < 4; ++i) s[kt][i] = sa[i] * scale;
    }
    __builtin_amdgcn_s_setprio(0);

    float alpha[4], rsm[4];
#pragma unroll
    for (int i = 0; i < 4; ++i) {
      float mx = fmaxf(fmaxf(s[0][i], s[1][i]), fmaxf(s[2][i], s[3][i]));
      mx = fmaxf(mx, __shfl_xor(mx, 1));
      mx = fmaxf(mx, __shfl_xor(mx, 2));
      mx = fmaxf(mx, __shfl_xor(mx, 4));
      mx = fmaxf(mx, __shfl_xor(mx, 8));
      float mn = fmaxf(m_[i], mx);
      alpha[i] = __expf(m_[i] - mn);
      m_[i] = mn;
      rsm[i] = 0.f;
    }
#pragma unroll
    for (int kt = 0; kt < 4; ++kt)
#pragma unroll
      for (int i = 0; i < 4; ++i) {
        float p = __expf(s[kt][i] - m_[i]);
        rsm[i] += p;
        Ps[w * 1152 + (g * 4 + i) * 72 + kt * 16 + c] = f2bf(p);
      }
#pragma unroll
    for (int i = 0; i < 4; ++i) {
      float r = rsm[i];
      r += __shfl_xor(r, 1); r += __shfl_xor(r, 2);
      r += __shfl_xor(r, 4); r += __shfl_xor(r, 8);
      l_[i] = l_[i] * alpha[i] + r;
    }
#pragma unroll
    for (int db = 0; db < 8; ++db)
#pragma unroll
      for (int i = 0; i < 4; ++i) acc[db][i] *= alpha[i];

    __builtin_amdgcn_s_setprio(1);
#pragma unroll
    for (int kf2 = 0; kf2 < 2; ++kf2) {
      bf16x8 pa = *(const bf16x8*)&Ps[w * 1152 + c * 72 + kf2 * 32 + g * 8];
#pragma unroll
      for (int db = 0; db < 8; ++db) {
        int row = db * 16 + c, colb = kf2 * 64 + g * 16;
        bf16x8 vb = *(const bf16x8*)(Vb + row * 128 + (colb ^ ((row & 7) << 4)));
        acc[db] = __builtin_amdgcn_mfma_f32_16x16x32_bf16(pa, vb, acc[db], 0, 0, 0);
      }
    }
    __builtin_amdgcn_s_setprio(0);
    cur ^= 1;
  }

  int b = bh >> 4, h = bh & 15;
#pragma unroll
  for (int i = 0; i < 4; ++i) l_[i] = 1.f / l_[i];
#pragma unroll
  for (int db = 0; db < 8; ++db)
#pragma unroll
    for (int i = 0; i < 4; ++i) {
      int r = q0 + g * 4 + i;
      attn[(size_t)(b * SEQ + r) * D_MODEL + h * HD + db * 16 + c] =
          f2bf(acc[db][i] * l_[i]);
    }
}

// ---------------- launch ----------------
extern "C" void kernel_launch(void* const* d_in, const int* in_sizes, int n_in,
                              void* d_out, int out_size, void* d_ws, size_t ws_size,
                              hipStream_t stream) {
  const float* hs   = (const float*)d_in[0];
  const float* fcos = (const float*)d_in[1];
  const float* fsin = (const float*)d_in[2];
  const float* Wq   = (const float*)d_in[3];
  const float* Wk   = (const float*)d_in[4];
  const float* Wv   = (const float*)d_in[5];
  const float* Wo   = (const float*)d_in[6];
  const float* gq   = (const float*)d_in[7];
  const float* gk   = (const float*)d_in[8];

  char* ws = (char*)d_ws;
  short* hs16  = (short*)ws;                        // 16,777,216 B
  short* Wt    = (short*)(ws + 16777216);           // 33,554,432 B (4 matrices, N-major)
  short* qkv16 = (short*)(ws + 50331648);           // 50,331,648 B (q,k,v bf16 token-major)
  short* qn    = (short*)(ws + 100663296);          // 16,777,216 B (B,H,S,128)
  short* kn    = (short*)(ws + 117440512);          // 16,777,216 B
  short* vt    = (short*)(ws + 134217728);          // 16,777,216 B (B,H,128,S)
  short* attn16 = qkv16;  // reuse q slot (dead after norm_rope)

  cast_bf16<<<8192, 256, 0, stream>>>(hs, hs16, NTOK * D_MODEL / 4);
  wtrans<<<dim3(32, 32, 4), 256, 0, stream>>>(Wq, Wk, Wv, Wo, Wt);
  gemm_bt<true><<<dim3(16, 32, 3), 256, 0, stream>>>(hs16, Wt, qkv16,
                                                     NTOK, D_MODEL, D_MODEL);
  norm_rope<<<dim3(16384, 2), 256, 0, stream>>>(qkv16, fcos, fsin, gq, gk, qn, kn);
  vtrans<<<dim3(32, 32), 256, 0, stream>>>(qkv16 + (size_t)2 * NTOK * D_MODEL, vt);
  flash<<<dim3(32, 32), 256, 0, stream>>>(qn, kn, vt, attn16);
  gemm_bt<false><<<dim3(16, 32, 1), 256, 0, stream>>>(attn16,
                                                      Wt + (size_t)3 * D_MODEL * D_MODEL,
                                                      d_out, NTOK, D_MODEL, D_MODEL);
}

// Round 3
// 355.234 us; speedup vs baseline: 1.4782x; 1.1567x over previous
//
#include <hip/hip_runtime.h>
#include <hip/hip_bf16.h>

typedef __attribute__((ext_vector_type(8))) short bf16x8;
typedef __attribute__((ext_vector_type(4))) short bf16x4;
typedef __attribute__((ext_vector_type(4))) float f32x4;
typedef __attribute__((ext_vector_type(4))) int   i32x4;
typedef __attribute__((ext_vector_type(2))) unsigned u32x2;

#define D_MODEL 2048
#define NTOK    4096   // B*S
#define NH      16
#define HD      128
#define SEQ     2048

__device__ __forceinline__ short f2bf(float f) {
  unsigned u = __builtin_bit_cast(unsigned, f);
  unsigned r = u + 0x7FFFu + ((u >> 16) & 1u);   // RNE
  return (short)(r >> 16);
}
__device__ __forceinline__ float bf2f(short s) {
  return __builtin_bit_cast(float, ((unsigned)(unsigned short)s) << 16);
}

__device__ __forceinline__ float exp2fast(float x) {
#if __has_builtin(__builtin_amdgcn_exp2f)
  return __builtin_amdgcn_exp2f(x);
#else
  return exp2f(x);
#endif
}

// pack 2 fp32 -> 2 bf16 (RNE) in one instr
__device__ __forceinline__ unsigned cvt_pk_bf16(float a, float b) {
  unsigned r;
  asm("v_cvt_pk_bf16_f32 %0, %1, %2" : "=v"(r) : "v"(a), "v"(b));
  return r;
}

#if __has_builtin(__builtin_amdgcn_mfma_f32_16x16x16bf16_1k)
#define MFMA16_ASM 0
__device__ __forceinline__ f32x4 mfma16(bf16x4 a, bf16x4 b, f32x4 c) {
  return __builtin_amdgcn_mfma_f32_16x16x16bf16_1k(a, b, c, 0, 0, 0);
}
#else
#define MFMA16_ASM 1
__device__ __forceinline__ f32x4 mfma16(bf16x4 a, bf16x4 b, f32x4 c) {
  asm("s_nop 3\n\tv_mfma_f32_16x16x16_bf16 %0, %1, %2, %0" : "+v"(c) : "v"(a), "v"(b));
  return c;
}
#endif

// async global->LDS, 16B per lane. LDS dst must be wave-uniform; HW writes lane i at dst + i*16.
__device__ __forceinline__ void gload_lds16(const void* g, void* l) {
  typedef __attribute__((address_space(1))) const unsigned gu32;
  typedef __attribute__((address_space(3))) unsigned lu32;
  __builtin_amdgcn_global_load_lds((gu32*)(uintptr_t)g,
                                   (lu32*)(unsigned)(uintptr_t)l, 16, 0, 0);
}

// ---------------- 1. fp32 -> bf16 cast (vectorized) ----------------
__global__ __launch_bounds__(256) void cast_bf16(const float* __restrict__ in,
                                                 short* __restrict__ out, int n4) {
  int i = blockIdx.x * 256 + threadIdx.x;
  if (i >= n4) return;
  float4 v = ((const float4*)in)[i];
  short4 o;
  o.x = f2bf(v.x); o.y = f2bf(v.y); o.z = f2bf(v.z); o.w = f2bf(v.w);
  ((short4*)out)[i] = o;
}

// ---------------- 2. W (KxN) -> W^T (NxK) bf16, LDS-tiled ----------------
__global__ __launch_bounds__(256) void wtrans(const float* __restrict__ w0,
                                              const float* __restrict__ w1,
                                              const float* __restrict__ w2,
                                              const float* __restrict__ w3,
                                              short* __restrict__ wt) {
  int z = blockIdx.z;
  const float* W = (z == 0) ? w0 : (z == 1) ? w1 : (z == 2) ? w2 : w3;
  short* O = wt + (size_t)z * D_MODEL * D_MODEL;
  int n0 = blockIdx.x * 64, k0 = blockIdx.y * 64;
  __shared__ short T[64 * 136];
  int tid = threadIdx.x;
#pragma unroll
  for (int it = 0; it < 4; ++it) {
    int f = it * 256 + tid, kk = f >> 4, nc = f & 15;
    float4 v = *(const float4*)&W[(size_t)(k0 + kk) * D_MODEL + n0 + nc * 4];
    short4 o;
    o.x = f2bf(v.x); o.y = f2bf(v.y); o.z = f2bf(v.z); o.w = f2bf(v.w);
    *(short4*)&T[kk * 136 + nc * 4] = o;
  }
  __syncthreads();
#pragma unroll
  for (int it = 0; it < 4; ++it) {
    int u = it * 256 + tid, nn = u >> 4, kc = u & 15;
    short4 o;
    o.x = T[(kc * 4 + 0) * 136 + nn];
    o.y = T[(kc * 4 + 1) * 136 + nn];
    o.z = T[(kc * 4 + 2) * 136 + nn];
    o.w = T[(kc * 4 + 3) * 136 + nn];
    *(short4*)&O[(size_t)(n0 + nn) * D_MODEL + k0 + kc * 4] = o;
  }
}

// ---------------- 3/7. GEMM  C[M,N] = A[M,K] * Bt[N,K]^T  (m97 structure) ----------------
template <bool OUTBF16>
__global__ __launch_bounds__(256) void gemm_bt(const short* __restrict__ A,
                                               const short* __restrict__ Bt,
                                               void* __restrict__ Cv,
                                               int M, int N, int K) {
  __shared__ short As[128 * 32];
  __shared__ short Bs[128 * 32];
  int tid = threadIdx.x;
  int w = tid >> 6, lane = tid & 63, c = lane & 15, g = lane >> 4;
  int z = blockIdx.z;
  const short* Bb = Bt + (size_t)z * K * N;
  int m0 = blockIdx.y * 128, n0 = blockIdx.x * 128;
  int wm = w >> 1, wn = w & 1;
  f32x4 acc[4][4] = {};
  int lrow = lane >> 2, lk = (lane & 3) * 8;

  for (int kk = 0; kk < K; kk += 32) {
    __syncthreads();
#pragma unroll
    for (int q = 0; q < 2; ++q) {
      int ch = 2 * w + q;  // wave-uniform chunk id (16 rows of 32 bf16 = 1KB)
      gload_lds16(A  + (size_t)(m0 + ch * 16 + lrow) * K + kk + lk, &As[ch * 512]);
      gload_lds16(Bb + (size_t)(n0 + ch * 16 + lrow) * K + kk + lk, &Bs[ch * 512]);
    }
    __syncthreads();
    bf16x8 af[4], bfr[4];
#pragma unroll
    for (int mi = 0; mi < 4; ++mi)
      af[mi] = *(const bf16x8*)&As[(wm * 64 + mi * 16 + c) * 32 + g * 8];
#pragma unroll
    for (int ni = 0; ni < 4; ++ni)
      bfr[ni] = *(const bf16x8*)&Bs[(wn * 64 + ni * 16 + c) * 32 + g * 8];
#pragma unroll
    for (int mi = 0; mi < 4; ++mi)
#pragma unroll
      for (int ni = 0; ni < 4; ++ni)
        acc[mi][ni] = __builtin_amdgcn_mfma_f32_16x16x32_bf16(af[mi], bfr[ni],
                                                              acc[mi][ni], 0, 0, 0);
  }
  int row0 = m0 + wm * 64, col0 = n0 + wn * 64;
  if (OUTBF16) {
    short* Cb = (short*)Cv + (size_t)z * M * N;
#pragma unroll
    for (int mi = 0; mi < 4; ++mi)
#pragma unroll
      for (int ni = 0; ni < 4; ++ni)
#pragma unroll
        for (int i = 0; i < 4; ++i)
          Cb[(size_t)(row0 + mi * 16 + g * 4 + i) * N + col0 + ni * 16 + c] =
              f2bf(acc[mi][ni][i]);
  } else {
    float* Cf = (float*)Cv;
#pragma unroll
    for (int mi = 0; mi < 4; ++mi)
#pragma unroll
      for (int ni = 0; ni < 4; ++ni)
#pragma unroll
        for (int i = 0; i < 4; ++i)
          Cf[(size_t)(row0 + mi * 16 + g * 4 + i) * N + col0 + ni * 16 + c] =
              acc[mi][ni][i];
  }
}

// ---------------- 4. fused RMSNorm + RoPE (q,k), one wave per (token,head) ----------------
// Q is pre-scaled by 1/sqrt(128)*log2(e) so flash's QK^T lands directly in the
// log2 domain (softmax uses raw v_exp 2^x) with the 1/sqrt(d) scale folded in.
__global__ __launch_bounds__(256) void norm_rope(const short* __restrict__ qkv16,
                                                 const float* __restrict__ cosb,
                                                 const float* __restrict__ sinb,
                                                 const float* __restrict__ gq,
                                                 const float* __restrict__ gk,
                                                 short* __restrict__ qn,
                                                 short* __restrict__ kn) {
  int z = blockIdx.y;  // 0=q, 1=k
  const short* X = qkv16 + (size_t)z * NTOK * D_MODEL;
  const float* gg = z ? gk : gq;
  short* O = z ? kn : qn;
  int w = threadIdx.x >> 6, lane = threadIdx.x & 63;
  int p = blockIdx.x * 4 + w;          // (token,head) pair
  int token = p >> 4, h = p & 15;
  int v = *(const int*)&X[(size_t)token * D_MODEL + h * HD + lane * 2];
  float x0 = bf2f((short)(v & 0xffff));
  float x1 = bf2f((short)((unsigned)v >> 16));
  float ss = x0 * x0 + x1 * x1;
#pragma unroll
  for (int mk = 32; mk; mk >>= 1) ss += __shfl_xor(ss, mk);
  float rs = rsqrtf(ss * (1.f / 128.f) + 1e-5f);
  float qs = z ? 1.0f : 0.12751744f;   // 1/sqrt(128) * log2(e) for Q only
  rs *= qs;
  float xr = x0 * rs * gg[lane * 2];
  float xi = x1 * rs * gg[lane * 2 + 1];
  float cc = cosb[(size_t)token * 64 + lane];
  float sn = sinb[(size_t)token * 64 + lane];
  float or_ = xr * cc - xi * sn;
  float oi_ = xr * sn + xi * cc;
  int b = token >> 11, sidx = token & 2047;
  size_t dst = ((size_t)(b * NH + h) * SEQ + sidx) * HD + lane * 2;
  unsigned pk = (unsigned)(unsigned short)f2bf(or_) |
                ((unsigned)(unsigned short)f2bf(oi_) << 16);
  *(unsigned*)&O[dst] = pk;
}

// ---------------- 5. V (token-major bf16) -> V^T (B,H,128,S) ----------------
__global__ __launch_bounds__(256) void vtrans(const short* __restrict__ v16,
                                              short* __restrict__ vt) {
  int st = blockIdx.x, bh = blockIdx.y;
  int b = bh >> 4, h = bh & 15;
  int t0 = b * SEQ + st * 64;
  __shared__ short Lt[64 * 136];
  int tid = threadIdx.x;
#pragma unroll
  for (int it = 0; it < 4; ++it) {
    int f = it * 256 + tid, tk = f >> 4, ch = f & 15;
    *(i32x4*)&Lt[tk * 136 + ch * 8] =
        *(const i32x4*)&v16[(size_t)(t0 + tk) * D_MODEL + h * HD + ch * 8];
  }
  __syncthreads();
#pragma unroll
  for (int it = 0; it < 4; ++it) {
    int u = it * 256 + tid, d = u >> 3, kg = u & 7;
    bf16x8 o;
#pragma unroll
    for (int j = 0; j < 8; ++j) o[j] = Lt[(kg * 8 + j) * 136 + d];
    *(bf16x8*)&vt[(size_t)(bh * HD + d) * SEQ + st * 64 + kg * 8] = o;
  }
}

// ---------------- 6. flash attention: swapped QK^T, in-register P, scalar softmax state ----------------
// 8 waves x 16 q-rows = 128 q/block. K tile [64 key][256B], V tile [128 d][128B],
// both XOR-swizzled (phys = row*RB + (col ^ ((row&7)<<4))), staged by global_load_lds
// with pre-swizzled source, double-buffered, 1 barrier/iter.
// QK^T: mfma32(K, Q) -> lane holds S[k = kt*16 + g*4 + i][q = c]  (log2-domain, Q pre-scaled)
// PV:   mfma16(Vt, P) with P packed in-register -> acc[d = db*16 + g*4 + i][q = c]
__global__ __launch_bounds__(512, 4) void flash(const short* __restrict__ qn,
                                                const short* __restrict__ kn,
                                                const short* __restrict__ vt,
                                                short* __restrict__ attn) {
  __shared__ short Ks[2][64 * 128];   // 2 x 16KB
  __shared__ short Vs[2][128 * 64];   // 2 x 16KB
  int tid = threadIdx.x, w = tid >> 6, lane = tid & 63, c = lane & 15, g = lane >> 4;
  int bh = blockIdx.y;
  int q0 = blockIdx.x * 128 + w * 16;
  const size_t base = (size_t)bh * SEQ * HD;
  const short* Kg = kn + base;
  const short* Vg = vt + base;

  bf16x8 qf[4];
#pragma unroll
  for (int kf = 0; kf < 4; ++kf)
    qf[kf] = *(const bf16x8*)&qn[base + (size_t)(q0 + c) * HD + kf * 32 + g * 8];

  f32x4 acc[8] = {};
  float m_ = -1e30f, l_ = 0.f;

  // staging: 16 K-chunks + 16 V-chunks of 1KB; wave w stages chunks {2w, 2w+1}
  int ksrc[2], vsrc[2];
#pragma unroll
  for (int p = 0; p < 2; ++p) {
    int ch = w * 2 + p;
    int o = ch * 1024 + lane * 16;                   // linear LDS byte offset
    int kr = o >> 8, kc = o & 255;                   // K: 256B rows
    ksrc[p] = kr * HD + ((kc ^ ((kr & 7) << 4)) >> 1);
    int vr = o >> 7, vc = o & 127;                   // V: 128B rows
    vsrc[p] = vr * SEQ + ((vc ^ ((vr & 7) << 4)) >> 1);
  }
  // read offsets (bytes), loop-invariant
  int swz = (c & 7) << 4;
  int koff[4], voff[4];
#pragma unroll
  for (int kf = 0; kf < 4; ++kf) koff[kf] = c * 256 + ((kf * 64 + g * 16) ^ swz);
#pragma unroll
  for (int kt = 0; kt < 4; ++kt) voff[kt] = c * 128 + ((kt * 32 + g * 8) ^ swz);

  // prologue: stage tile 0 into buffer 0
#pragma unroll
  for (int p = 0; p < 2; ++p) {
    int ch = w * 2 + p;
    gload_lds16(Kg + ksrc[p], (char*)&Ks[0][0] + ch * 1024);
    gload_lds16(Vg + vsrc[p], (char*)&Vs[0][0] + ch * 1024);
  }

  const int NT = SEQ / 64;
  for (int t = 0; t < NT; ++t) {
    int cur = t & 1;
    __syncthreads();           // vmcnt(0) drain => buf[cur] ready; buf[cur^1] free
    if (t + 1 < NT) {
      int k0n = (t + 1) * 64;
#pragma unroll
      for (int p = 0; p < 2; ++p) {
        int ch = w * 2 + p;
        gload_lds16(Kg + (size_t)k0n * HD + ksrc[p], (char*)&Ks[cur ^ 1][0] + ch * 1024);
        gload_lds16(Vg + k0n + vsrc[p],              (char*)&Vs[cur ^ 1][0] + ch * 1024);
      }
    }
    const char* Kb = (const char*)&Ks[cur][0];
    const char* Vb = (const char*)&Vs[cur][0];

    // QK^T (swapped): s[kt] lane(c,g)[i] = S[kt*16 + g*4 + i][q0 + c], log2 domain
    f32x4 s[4];
    __builtin_amdgcn_s_setprio(1);
#pragma unroll
    for (int kt = 0; kt < 4; ++kt) {
      f32x4 sa = {0.f, 0.f, 0.f, 0.f};
#pragma unroll
      for (int kf = 0; kf < 4; ++kf) {
        bf16x8 kb = *(const bf16x8*)(Kb + kt * 4096 + koff[kf]);
        sa = __builtin_amdgcn_mfma_f32_16x16x32_bf16(kb, qf[kf], sa, 0, 0, 0);
      }
      s[kt] = sa;
    }
    __builtin_amdgcn_s_setprio(0);

    // per-lane scalar online softmax (q = c)
    float pmax = -1e30f;
#pragma unroll
    for (int kt = 0; kt < 4; ++kt)
#pragma unroll
      for (int i = 0; i < 4; ++i) pmax = fmaxf(pmax, s[kt][i]);
    pmax = fmaxf(pmax, __shfl_xor(pmax, 16));
    pmax = fmaxf(pmax, __shfl_xor(pmax, 32));
    if (!__all(pmax <= m_ + 11.5f)) {   // defer-max: p bounded by 2^11.5
      float mn = fmaxf(m_, pmax);
      float al = exp2fast(m_ - mn);
      m_ = mn; l_ *= al;
#pragma unroll
      for (int db = 0; db < 8; ++db)
#pragma unroll
        for (int i = 0; i < 4; ++i) acc[db][i] *= al;
    }
    float r = 0.f;
#pragma unroll
    for (int kt = 0; kt < 4; ++kt)
#pragma unroll
      for (int i = 0; i < 4; ++i) {
        float p = exp2fast(s[kt][i] - m_);
        r += p; s[kt][i] = p;
      }
    r += __shfl_xor(r, 16);
    r += __shfl_xor(r, 32);
    l_ += r;

    // pack P to bf16 in-register: pb[kt] = B-fragment of mfma16 (P[k][q=c])
    bf16x4 pb[4];
#pragma unroll
    for (int kt = 0; kt < 4; ++kt) {
      u32x2 tpk;
      tpk[0] = cvt_pk_bf16(s[kt][0], s[kt][1]);
      tpk[1] = cvt_pk_bf16(s[kt][2], s[kt][3]);
      pb[kt] = __builtin_bit_cast(bf16x4, tpk);
    }

    // PV: acc[db] += Vt-frag x pb  (16x16x16)
    __builtin_amdgcn_s_setprio(1);
#pragma unroll
    for (int kt = 0; kt < 4; ++kt)
#pragma unroll
      for (int db = 0; db < 8; ++db) {
        bf16x4 va = *(const bf16x4*)(Vb + db * 2048 + voff[kt]);
        acc[db] = mfma16(va, pb[kt], acc[db]);
      }
    __builtin_amdgcn_s_setprio(0);
  }
#if MFMA16_ASM
  asm volatile("s_nop 7\n\ts_nop 7");
#endif

  int b = bh >> 4, h = bh & 15;
  float linv = 1.f / l_;
#pragma unroll
  for (int db = 0; db < 8; ++db) {
    short4 o;
    o.x = f2bf(acc[db][0] * linv);
    o.y = f2bf(acc[db][1] * linv);
    o.z = f2bf(acc[db][2] * linv);
    o.w = f2bf(acc[db][3] * linv);
    *(short4*)&attn[(size_t)(b * SEQ + q0 + c) * D_MODEL + h * HD + db * 16 + g * 4] = o;
  }
}

// ---------------- launch ----------------
extern "C" void kernel_launch(void* const* d_in, const int* in_sizes, int n_in,
                              void* d_out, int out_size, void* d_ws, size_t ws_size,
                              hipStream_t stream) {
  const float* hs   = (const float*)d_in[0];
  const float* fcos = (const float*)d_in[1];
  const float* fsin = (const float*)d_in[2];
  const float* Wq   = (const float*)d_in[3];
  const float* Wk   = (const float*)d_in[4];
  const float* Wv   = (const float*)d_in[5];
  const float* Wo   = (const float*)d_in[6];
  const float* gq   = (const float*)d_in[7];
  const float* gk   = (const float*)d_in[8];

  char* ws = (char*)d_ws;
  short* hs16  = (short*)ws;                        // 16,777,216 B
  short* Wt    = (short*)(ws + 16777216);           // 33,554,432 B (4 matrices, N-major)
  short* qkv16 = (short*)(ws + 50331648);           // 50,331,648 B (q,k,v bf16 token-major)
  short* qn    = (short*)(ws + 100663296);          // 16,777,216 B (B,H,S,128)
  short* kn    = (short*)(ws + 117440512);          // 16,777,216 B
  short* vt    = (short*)(ws + 134217728);          // 16,777,216 B (B,H,128,S)
  short* attn16 = qkv16;  // reuse q slot (dead after norm_rope)

  cast_bf16<<<8192, 256, 0, stream>>>(hs, hs16, NTOK * D_MODEL / 4);
  wtrans<<<dim3(32, 32, 4), 256, 0, stream>>>(Wq, Wk, Wv, Wo, Wt);
  gemm_bt<true><<<dim3(16, 32, 3), 256, 0, stream>>>(hs16, Wt, qkv16,
                                                     NTOK, D_MODEL, D_MODEL);
  norm_rope<<<dim3(16384, 2), 256, 0, stream>>>(qkv16, fcos, fsin, gq, gk, qn, kn);
  vtrans<<<dim3(32, 32), 256, 0, stream>>>(qkv16 + (size_t)2 * NTOK * D_MODEL, vt);
  flash<<<dim3(16, 32), 512, 0, stream>>>(qn, kn, vt, attn16);
  gemm_bt<false><<<dim3(16, 32, 1), 256, 0, stream>>>(attn16,
                                                      Wt + (size_t)3 * D_MODEL * D_MODEL,
                                                      d_out, NTOK, D_MODEL, D_MODEL);
}

// Round 4
// 354.651 us; speedup vs baseline: 1.4806x; 1.0016x over previous
//
#include <hip/hip_runtime.h>
#include <hip/hip_bf16.h>

typedef __attribute__((ext_vector_type(8))) short bf16x8;
typedef __attribute__((ext_vector_type(4))) short bf16x4;
typedef __attribute__((ext_vector_type(4))) float f32x4;
typedef __attribute__((ext_vector_type(4))) int   i32x4;
typedef __attribute__((ext_vector_type(2))) unsigned u32x2;

#define D_MODEL 2048
#define NTOK    4096   // B*S
#define NH      16
#define HD      128
#define SEQ     2048

__device__ __forceinline__ short f2bf(float f) {
  unsigned u = __builtin_bit_cast(unsigned, f);
  unsigned r = u + 0x7FFFu + ((u >> 16) & 1u);   // RNE
  return (short)(r >> 16);
}
__device__ __forceinline__ float bf2f(short s) {
  return __builtin_bit_cast(float, ((unsigned)(unsigned short)s) << 16);
}

__device__ __forceinline__ float exp2fast(float x) {
#if __has_builtin(__builtin_amdgcn_exp2f)
  return __builtin_amdgcn_exp2f(x);
#else
  return exp2f(x);
#endif
}

// pack 2 fp32 -> 2 bf16 (RNE) in one instr
__device__ __forceinline__ unsigned cvt_pk_bf16(float a, float b) {
  unsigned r;
  asm("v_cvt_pk_bf16_f32 %0, %1, %2" : "=v"(r) : "v"(a), "v"(b));
  return r;
}

#if __has_builtin(__builtin_amdgcn_mfma_f32_16x16x16bf16_1k)
#define MFMA16_ASM 0
__device__ __forceinline__ f32x4 mfma16(bf16x4 a, bf16x4 b, f32x4 c) {
  return __builtin_amdgcn_mfma_f32_16x16x16bf16_1k(a, b, c, 0, 0, 0);
}
#else
#define MFMA16_ASM 1
__device__ __forceinline__ f32x4 mfma16(bf16x4 a, bf16x4 b, f32x4 c) {
  asm("s_nop 3\n\tv_mfma_f32_16x16x16_bf16 %0, %1, %2, %0" : "+v"(c) : "v"(a), "v"(b));
  return c;
}
#endif

// async global->LDS, 16B per lane. LDS dst must be wave-uniform; HW writes lane i at dst + i*16.
__device__ __forceinline__ void gload_lds16(const void* g, void* l) {
  typedef __attribute__((address_space(1))) const unsigned gu32;
  typedef __attribute__((address_space(3))) unsigned lu32;
  __builtin_amdgcn_global_load_lds((gu32*)(uintptr_t)g,
                                   (lu32*)(unsigned)(uintptr_t)l, 16, 0, 0);
}

// ---------------- 1. fp32 -> bf16 cast (vectorized) ----------------
__global__ __launch_bounds__(256) void cast_bf16(const float* __restrict__ in,
                                                 short* __restrict__ out, int n4) {
  int i = blockIdx.x * 256 + threadIdx.x;
  if (i >= n4) return;
  float4 v = ((const float4*)in)[i];
  short4 o;
  o.x = f2bf(v.x); o.y = f2bf(v.y); o.z = f2bf(v.z); o.w = f2bf(v.w);
  ((short4*)out)[i] = o;
}

// ---------------- 2. W (KxN) -> W^T (NxK) bf16, LDS-tiled ----------------
__global__ __launch_bounds__(256) void wtrans(const float* __restrict__ w0,
                                              const float* __restrict__ w1,
                                              const float* __restrict__ w2,
                                              const float* __restrict__ w3,
                                              short* __restrict__ wt) {
  int z = blockIdx.z;
  const float* W = (z == 0) ? w0 : (z == 1) ? w1 : (z == 2) ? w2 : w3;
  short* O = wt + (size_t)z * D_MODEL * D_MODEL;
  int n0 = blockIdx.x * 64, k0 = blockIdx.y * 64;
  __shared__ short T[64 * 136];
  int tid = threadIdx.x;
#pragma unroll
  for (int it = 0; it < 4; ++it) {
    int f = it * 256 + tid, kk = f >> 4, nc = f & 15;
    float4 v = *(const float4*)&W[(size_t)(k0 + kk) * D_MODEL + n0 + nc * 4];
    short4 o;
    o.x = f2bf(v.x); o.y = f2bf(v.y); o.z = f2bf(v.z); o.w = f2bf(v.w);
    *(short4*)&T[kk * 136 + nc * 4] = o;
  }
  __syncthreads();
#pragma unroll
  for (int it = 0; it < 4; ++it) {
    int u = it * 256 + tid, nn = u >> 4, kc = u & 15;
    short4 o;
    o.x = T[(kc * 4 + 0) * 136 + nn];
    o.y = T[(kc * 4 + 1) * 136 + nn];
    o.z = T[(kc * 4 + 2) * 136 + nn];
    o.w = T[(kc * 4 + 3) * 136 + nn];
    *(short4*)&O[(size_t)(n0 + nn) * D_MODEL + k0 + kc * 4] = o;
  }
}

// ---------------- 3/7. GEMM  C[M,N] = A[M,K] * Bt[N,K]^T  (m97 structure) ----------------
template <bool OUTBF16>
__global__ __launch_bounds__(256) void gemm_bt(const short* __restrict__ A,
                                               const short* __restrict__ Bt,
                                               void* __restrict__ Cv,
                                               int M, int N, int K) {
  __shared__ short As[128 * 32];
  __shared__ short Bs[128 * 32];
  int tid = threadIdx.x;
  int w = tid >> 6, lane = tid & 63, c = lane & 15, g = lane >> 4;
  int z = blockIdx.z;
  const short* Bb = Bt + (size_t)z * K * N;
  int m0 = blockIdx.y * 128, n0 = blockIdx.x * 128;
  int wm = w >> 1, wn = w & 1;
  f32x4 acc[4][4] = {};
  int lrow = lane >> 2, lk = (lane & 3) * 8;

  for (int kk = 0; kk < K; kk += 32) {
    __syncthreads();
#pragma unroll
    for (int q = 0; q < 2; ++q) {
      int ch = 2 * w + q;  // wave-uniform chunk id (16 rows of 32 bf16 = 1KB)
      gload_lds16(A  + (size_t)(m0 + ch * 16 + lrow) * K + kk + lk, &As[ch * 512]);
      gload_lds16(Bb + (size_t)(n0 + ch * 16 + lrow) * K + kk + lk, &Bs[ch * 512]);
    }
    __syncthreads();
    bf16x8 af[4], bfr[4];
#pragma unroll
    for (int mi = 0; mi < 4; ++mi)
      af[mi] = *(const bf16x8*)&As[(wm * 64 + mi * 16 + c) * 32 + g * 8];
#pragma unroll
    for (int ni = 0; ni < 4; ++ni)
      bfr[ni] = *(const bf16x8*)&Bs[(wn * 64 + ni * 16 + c) * 32 + g * 8];
#pragma unroll
    for (int mi = 0; mi < 4; ++mi)
#pragma unroll
      for (int ni = 0; ni < 4; ++ni)
        acc[mi][ni] = __builtin_amdgcn_mfma_f32_16x16x32_bf16(af[mi], bfr[ni],
                                                              acc[mi][ni], 0, 0, 0);
  }
  int row0 = m0 + wm * 64, col0 = n0 + wn * 64;
  if (OUTBF16) {
    short* Cb = (short*)Cv + (size_t)z * M * N;
#pragma unroll
    for (int mi = 0; mi < 4; ++mi)
#pragma unroll
      for (int ni = 0; ni < 4; ++ni)
#pragma unroll
        for (int i = 0; i < 4; ++i)
          Cb[(size_t)(row0 + mi * 16 + g * 4 + i) * N + col0 + ni * 16 + c] =
              f2bf(acc[mi][ni][i]);
  } else {
    float* Cf = (float*)Cv;
#pragma unroll
    for (int mi = 0; mi < 4; ++mi)
#pragma unroll
      for (int ni = 0; ni < 4; ++ni)
#pragma unroll
        for (int i = 0; i < 4; ++i)
          Cf[(size_t)(row0 + mi * 16 + g * 4 + i) * N + col0 + ni * 16 + c] =
              acc[mi][ni][i];
  }
}

// ---------------- 4. fused RMSNorm + RoPE (q,k), one wave per (token,head) ----------------
// Q is pre-scaled by 1/sqrt(128)*log2(e) so flash's QK^T lands directly in the
// log2 domain (softmax uses raw v_exp 2^x) with the 1/sqrt(d) scale folded in.
__global__ __launch_bounds__(256) void norm_rope(const short* __restrict__ qkv16,
                                                 const float* __restrict__ cosb,
                                                 const float* __restrict__ sinb,
                                                 const float* __restrict__ gq,
                                                 const float* __restrict__ gk,
                                                 short* __restrict__ qn,
                                                 short* __restrict__ kn) {
  int z = blockIdx.y;  // 0=q, 1=k
  const short* X = qkv16 + (size_t)z * NTOK * D_MODEL;
  const float* gg = z ? gk : gq;
  short* O = z ? kn : qn;
  int w = threadIdx.x >> 6, lane = threadIdx.x & 63;
  int p = blockIdx.x * 4 + w;          // (token,head) pair
  int token = p >> 4, h = p & 15;
  int v = *(const int*)&X[(size_t)token * D_MODEL + h * HD + lane * 2];
  float x0 = bf2f((short)(v & 0xffff));
  float x1 = bf2f((short)((unsigned)v >> 16));
  float ss = x0 * x0 + x1 * x1;
#pragma unroll
  for (int mk = 32; mk; mk >>= 1) ss += __shfl_xor(ss, mk);
  float rs = rsqrtf(ss * (1.f / 128.f) + 1e-5f);
  float qs = z ? 1.0f : 0.12751744f;   // 1/sqrt(128) * log2(e) for Q only
  rs *= qs;
  float xr = x0 * rs * gg[lane * 2];
  float xi = x1 * rs * gg[lane * 2 + 1];
  float cc = cosb[(size_t)token * 64 + lane];
  float sn = sinb[(size_t)token * 64 + lane];
  float or_ = xr * cc - xi * sn;
  float oi_ = xr * sn + xi * cc;
  int b = token >> 11, sidx = token & 2047;
  size_t dst = ((size_t)(b * NH + h) * SEQ + sidx) * HD + lane * 2;
  unsigned pk = (unsigned)(unsigned short)f2bf(or_) |
                ((unsigned)(unsigned short)f2bf(oi_) << 16);
  *(unsigned*)&O[dst] = pk;
}

// ---------------- 5. V (token-major bf16) -> V^T (B,H,128,S) ----------------
__global__ __launch_bounds__(256) void vtrans(const short* __restrict__ v16,
                                              short* __restrict__ vt) {
  int st = blockIdx.x, bh = blockIdx.y;
  int b = bh >> 4, h = bh & 15;
  int t0 = b * SEQ + st * 64;
  __shared__ short Lt[64 * 136];
  int tid = threadIdx.x;
#pragma unroll
  for (int it = 0; it < 4; ++it) {
    int f = it * 256 + tid, tk = f >> 4, ch = f & 15;
    *(i32x4*)&Lt[tk * 136 + ch * 8] =
        *(const i32x4*)&v16[(size_t)(t0 + tk) * D_MODEL + h * HD + ch * 8];
  }
  __syncthreads();
#pragma unroll
  for (int it = 0; it < 4; ++it) {
    int u = it * 256 + tid, d = u >> 3, kg = u & 7;
    bf16x8 o;
#pragma unroll
    for (int j = 0; j < 8; ++j) o[j] = Lt[(kg * 8 + j) * 136 + d];
    *(bf16x8*)&vt[(size_t)(bh * HD + d) * SEQ + st * 64 + kg * 8] = o;
  }
}

// ---------------- 6. flash attention: swapped QK^T, in-register P, scalar softmax state ----------------
// 8 waves x 16 q-rows = 128 q/block. K tile [64 key][256B], V tile [128 d][128B],
// both XOR-swizzled (phys = row*RB + (col ^ ((row&7)<<4))), staged by global_load_lds
// with pre-swizzled source, double-buffered, 1 barrier/iter.
// QK^T: mfma32(K, Q) -> lane holds S[k = kt*16 + g*4 + i][q = c]  (log2-domain, Q pre-scaled)
// PV:   mfma16(Vt, P) with P packed in-register -> acc[d = db*16 + g*4 + i][q = c]
__global__ __launch_bounds__(512, 4) void flash(const short* __restrict__ qn,
                                                const short* __restrict__ kn,
                                                const short* __restrict__ vt,
                                                short* __restrict__ attn) {
  __shared__ short Ks[2][64 * 128];   // 2 x 16KB
  __shared__ short Vs[2][128 * 64];   // 2 x 16KB
  int tid = threadIdx.x, w = tid >> 6, lane = tid & 63, c = lane & 15, g = lane >> 4;
  int bh = blockIdx.y;
  int q0 = blockIdx.x * 128 + w * 16;
  const size_t base = (size_t)bh * SEQ * HD;
  const short* Kg = kn + base;
  const short* Vg = vt + base;

  bf16x8 qf[4];
#pragma unroll
  for (int kf = 0; kf < 4; ++kf)
    qf[kf] = *(const bf16x8*)&qn[base + (size_t)(q0 + c) * HD + kf * 32 + g * 8];

  f32x4 acc[8] = {};
  float m_ = -1e30f, l_ = 0.f;

  // staging: 16 K-chunks + 16 V-chunks of 1KB; wave w stages chunks {2w, 2w+1}
  int ksrc[2], vsrc[2];
#pragma unroll
  for (int p = 0; p < 2; ++p) {
    int ch = w * 2 + p;
    int o = ch * 1024 + lane * 16;                   // linear LDS byte offset
    int kr = o >> 8, kc = o & 255;                   // K: 256B rows
    ksrc[p] = kr * HD + ((kc ^ ((kr & 7) << 4)) >> 1);
    int vr = o >> 7, vc = o & 127;                   // V: 128B rows
    vsrc[p] = vr * SEQ + ((vc ^ ((vr & 7) << 4)) >> 1);
  }
  // read offsets (bytes), loop-invariant
  int swz = (c & 7) << 4;
  int koff[4], voff[4];
#pragma unroll
  for (int kf = 0; kf < 4; ++kf) koff[kf] = c * 256 + ((kf * 64 + g * 16) ^ swz);
#pragma unroll
  for (int kt = 0; kt < 4; ++kt) voff[kt] = c * 128 + ((kt * 32 + g * 8) ^ swz);

  // prologue: stage tile 0 into buffer 0
#pragma unroll
  for (int p = 0; p < 2; ++p) {
    int ch = w * 2 + p;
    gload_lds16(Kg + ksrc[p], (char*)&Ks[0][0] + ch * 1024);
    gload_lds16(Vg + vsrc[p], (char*)&Vs[0][0] + ch * 1024);
  }

  const int NT = SEQ / 64;
  for (int t = 0; t < NT; ++t) {
    int cur = t & 1;
    __syncthreads();           // vmcnt(0) drain => buf[cur] ready; buf[cur^1] free
    if (t + 1 < NT) {
      int k0n = (t + 1) * 64;
#pragma unroll
      for (int p = 0; p < 2; ++p) {
        int ch = w * 2 + p;
        gload_lds16(Kg + (size_t)k0n * HD + ksrc[p], (char*)&Ks[cur ^ 1][0] + ch * 1024);
        gload_lds16(Vg + k0n + vsrc[p],              (char*)&Vs[cur ^ 1][0] + ch * 1024);
      }
    }
    const char* Kb = (const char*)&Ks[cur][0];
    const char* Vb = (const char*)&Vs[cur][0];

    // QK^T (swapped): s[kt] lane(c,g)[i] = S[kt*16 + g*4 + i][q0 + c], log2 domain
    f32x4 s[4];
    __builtin_amdgcn_s_setprio(1);
#pragma unroll
    for (int kt = 0; kt < 4; ++kt) {
      f32x4 sa = {0.f, 0.f, 0.f, 0.f};
#pragma unroll
      for (int kf = 0; kf < 4; ++kf) {
        bf16x8 kb = *(const bf16x8*)(Kb + kt * 4096 + koff[kf]);
        sa = __builtin_amdgcn_mfma_f32_16x16x32_bf16(kb, qf[kf], sa, 0, 0, 0);
      }
      s[kt] = sa;
    }
    __builtin_amdgcn_s_setprio(0);

    // per-lane scalar online softmax (q = c)
    float pmax = -1e30f;
#pragma unroll
    for (int kt = 0; kt < 4; ++kt)
#pragma unroll
      for (int i = 0; i < 4; ++i) pmax = fmaxf(pmax, s[kt][i]);
    pmax = fmaxf(pmax, __shfl_xor(pmax, 16));
    pmax = fmaxf(pmax, __shfl_xor(pmax, 32));
    if (!__all(pmax <= m_ + 11.5f)) {   // defer-max: p bounded by 2^11.5
      float mn = fmaxf(m_, pmax);
      float al = exp2fast(m_ - mn);
      m_ = mn; l_ *= al;
#pragma unroll
      for (int db = 0; db < 8; ++db)
#pragma unroll
        for (int i = 0; i < 4; ++i) acc[db][i] *= al;
    }
    float r = 0.f;
#pragma unroll
    for (int kt = 0; kt < 4; ++kt)
#pragma unroll
      for (int i = 0; i < 4; ++i) {
        float p = exp2fast(s[kt][i] - m_);
        r += p; s[kt][i] = p;
      }
    r += __shfl_xor(r, 16);
    r += __shfl_xor(r, 32);
    l_ += r;

    // pack P to bf16 in-register: pb[kt] = B-fragment of mfma16 (P[k][q=c])
    bf16x4 pb[4];
#pragma unroll
    for (int kt = 0; kt < 4; ++kt) {
      u32x2 tpk;
      tpk[0] = cvt_pk_bf16(s[kt][0], s[kt][1]);
      tpk[1] = cvt_pk_bf16(s[kt][2], s[kt][3]);
      pb[kt] = __builtin_bit_cast(bf16x4, tpk);
    }

    // PV: acc[db] += Vt-frag x pb  (16x16x16)
    __builtin_amdgcn_s_setprio(1);
#pragma unroll
    for (int kt = 0; kt < 4; ++kt)
#pragma unroll
      for (int db = 0; db < 8; ++db) {
        bf16x4 va = *(const bf16x4*)(Vb + db * 2048 + voff[kt]);
        acc[db] = mfma16(va, pb[kt], acc[db]);
      }
    __builtin_amdgcn_s_setprio(0);
  }
#if MFMA16_ASM
  asm volatile("s_nop 7\n\ts_nop 7");
#endif

  int b = bh >> 4, h = bh & 15;
  float linv = 1.f / l_;
#pragma unroll
  for (int db = 0; db < 8; ++db) {
    short4 o;
    o.x = f2bf(acc[db][0] * linv);
    o.y = f2bf(acc[db][1] * linv);
    o.z = f2bf(acc[db][2] * linv);
    o.w = f2bf(acc[db][3] * linv);
    *(short4*)&attn[(size_t)(b * SEQ + q0 + c) * D_MODEL + h * HD + db * 16 + g * 4] = o;
  }
}

// ---------------- launch ----------------
extern "C" void kernel_launch(void* const* d_in, const int* in_sizes, int n_in,
                              void* d_out, int out_size, void* d_ws, size_t ws_size,
                              hipStream_t stream) {
  const float* hs   = (const float*)d_in[0];
  const float* fcos = (const float*)d_in[1];
  const float* fsin = (const float*)d_in[2];
  const float* Wq   = (const float*)d_in[3];
  const float* Wk   = (const float*)d_in[4];
  const float* Wv   = (const float*)d_in[5];
  const float* Wo   = (const float*)d_in[6];
  const float* gq   = (const float*)d_in[7];
  const float* gk   = (const float*)d_in[8];

  char* ws = (char*)d_ws;
  short* hs16  = (short*)ws;                        // 16,777,216 B
  short* Wt    = (short*)(ws + 16777216);           // 33,554,432 B (4 matrices, N-major)
  short* qkv16 = (short*)(ws + 50331648);           // 50,331,648 B (q,k,v bf16 token-major)
  short* qn    = (short*)(ws + 100663296);          // 16,777,216 B (B,H,S,128)
  short* kn    = (short*)(ws + 117440512);          // 16,777,216 B
  short* vt    = (short*)(ws + 134217728);          // 16,777,216 B (B,H,128,S)
  short* attn16 = qkv16;  // reuse q slot (dead after norm_rope)

  cast_bf16<<<8192, 256, 0, stream>>>(hs, hs16, NTOK * D_MODEL / 4);
  wtrans<<<dim3(32, 32, 4), 256, 0, stream>>>(Wq, Wk, Wv, Wo, Wt);
  gemm_bt<true><<<dim3(16, 32, 3), 256, 0, stream>>>(hs16, Wt, qkv16,
                                                     NTOK, D_MODEL, D_MODEL);
  norm_rope<<<dim3(16384, 2), 256, 0, stream>>>(qkv16, fcos, fsin, gq, gk, qn, kn);
  vtrans<<<dim3(32, 32), 256, 0, stream>>>(qkv16 + (size_t)2 * NTOK * D_MODEL, vt);
  flash<<<dim3(16, 32), 512, 0, stream>>>(qn, kn, vt, attn16);
  gemm_bt<false><<<dim3(16, 32, 1), 256, 0, stream>>>(attn16,
                                                      Wt + (size_t)3 * D_MODEL * D_MODEL,
                                                      d_out, NTOK, D_MODEL, D_MODEL);
}